// Round 20
// baseline (176.564 us; speedup 1.0000x reference)
//
#include <hip/hip_runtime.h>
#include <hip/hip_bf16.h>

#define D_MODEL 768
#define NH 12
#define DHd 64
#define NB 2
#define SL 4096
#define BLr (NB*SL)      // 8192 rows
#define N3 (3*D_MODEL)   // 2304
#define QSCALE 0.18033688011112042f   // 0.125 * log2(e): softmax in log2 domain

typedef __bf16 bf16x8 __attribute__((ext_vector_type(8)));
typedef float f32x4 __attribute__((ext_vector_type(4)));
typedef float f32x16 __attribute__((ext_vector_type(16)));
typedef unsigned int u32x4 __attribute__((ext_vector_type(4)));

__device__ __forceinline__ unsigned short f2bf(float f) {
  unsigned int u = __float_as_uint(f);
  u = (u + 0x7FFFu + ((u >> 16) & 1u)) >> 16;
  return (unsigned short)u;
}
__device__ __forceinline__ unsigned short bfc(float f) {
  __bf16 h = (__bf16)f;
  return __builtin_bit_cast(unsigned short, h);
}
__device__ __forceinline__ float fexp2(float x) {
  float r; asm("v_exp_f32 %0, %1" : "=v"(r) : "v"(x)); return r;
}
// packed bf16 conversion: dst.lo = bf16(lo), dst.hi = bf16(hi) — single VALU op
__device__ __forceinline__ unsigned int pk2(float lo, float hi2) {
  unsigned int r;
  asm("v_cvt_pk_bf16_f32 %0, %1, %2" : "=v"(r) : "v"(lo), "v"(hi2));
  return r;
}
// async global->LDS, 16B per lane; LDS dest = wave-uniform base + lane*16
__device__ __forceinline__ void gload_lds16(const void* g, void* l) {
  __builtin_amdgcn_global_load_lds(
      (const __attribute__((address_space(1))) void*)g,
      (__attribute__((address_space(3))) void*)l, 16, 0, 0);
}

// ---------------- prep kernels ----------------
__global__ __launch_bounds__(256) void cast_f32_bf16(const float* __restrict__ in,
                                                     unsigned short* __restrict__ out, int n4) {
  int i = blockIdx.x * 256 + threadIdx.x;
  if (i >= n4) return;
  float4 v = reinterpret_cast<const float4*>(in)[i];
  ushort4 o;
  o.x = f2bf(v.x); o.y = f2bf(v.y); o.z = f2bf(v.z); o.w = f2bf(v.w);
  reinterpret_cast<ushort4*>(out)[i] = o;
}

// fused: transpose+cast w_qkv (768x2304 -> [2304][768]) and w_out (768x768)
__global__ __launch_bounds__(256) void transpose_cast2(const float* __restrict__ wq,
                                                       unsigned short* __restrict__ oq,
                                                       const float* __restrict__ wo,
                                                       unsigned short* __restrict__ oo) {
  __shared__ float t[32][33];
  const int bx = blockIdx.x;
  const float* in; unsigned short* out; int R, C, c0;
  if (bx < 72) { in = wq; out = oq; R = 768; C = 2304; c0 = bx * 32; }
  else         { in = wo; out = oo; R = 768; C = 768;  c0 = (bx - 72) * 32; }
  int r0 = blockIdx.y * 32;
  int tx = threadIdx.x & 31, ty = threadIdx.x >> 5;
  #pragma unroll
  for (int i = 0; i < 32; i += 8) t[ty + i][tx] = in[(size_t)(r0 + ty + i) * C + c0 + tx];
  __syncthreads();
  #pragma unroll
  for (int i = 0; i < 32; i += 8) out[(size_t)(c0 + ty + i) * R + r0 + tx] = f2bf(t[tx][ty + i]);
}

// ---------------- GEMM1 (128x128, 4 waves): QKV fragment-tiled epilogue -----
// 2 x BK=32 K-steps per barrier pair (4 single-buffers): halves barrier count,
// keeps the proven 64B-row LDS layout (no new bank-conflict surface).
// Q/K blocks: LDS-staged epilogue -> coalesced 16B fragment-tile stores.
// V blocks: proven direct scatter (permuted layout).
__global__ __launch_bounds__(256) void gemm_qkv(const unsigned short* __restrict__ A,
                                                const unsigned short* __restrict__ Bt,
                                                const float* __restrict__ bias,
                                                unsigned short* __restrict__ Qf,
                                                unsigned short* __restrict__ Kf,
                                                unsigned short* __restrict__ Vf,
                                                int M, int N, int Kdim) {
  __shared__ unsigned short smem[128 * 136];   // 4x8KB stage bufs; Cs overlay after
  unsigned short* As0 = smem;
  unsigned short* As1 = smem + 128 * 32;
  unsigned short* Bs0 = smem + 2 * 128 * 32;
  unsigned short* Bs1 = smem + 3 * 128 * 32;
  const int tid = threadIdx.x;
  const int lane = tid & 63, wave = tid >> 6;
  const int tm = blockIdx.x * 128, tn = blockIdx.y * 128;
  const int wm = (wave >> 1) * 64, wn = (wave & 1) * 64;
  const int fr = lane & 15, fk8 = (lane >> 4) * 8;
  const int srow = wave * 32 + (lane >> 2);
  const int scol = (lane & 3) * 8;

  f32x4 acc[4][4] = {};

  auto compute = [&](const unsigned short* Asb, const unsigned short* Bsb) {
    bf16x8 af[4], bfr[4];
    #pragma unroll
    for (int i = 0; i < 4; i++) {
      af[i]  = *(const bf16x8*)(Asb + (wm + i * 16 + fr) * 32 + fk8);
      bfr[i] = *(const bf16x8*)(Bsb + (wn + i * 16 + fr) * 32 + fk8);
    }
    #pragma unroll
    for (int i = 0; i < 4; i++)
      #pragma unroll
      for (int j = 0; j < 4; j++)
        acc[i][j] = __builtin_amdgcn_mfma_f32_16x16x32_bf16(af[i], bfr[j], acc[i][j], 0, 0, 0);
  };

  for (int k0 = 0; k0 < Kdim; k0 += 64) {
    __syncthreads();
    gload_lds16(A  + (size_t)(tm + srow)      * Kdim + k0 + scol,      As0 + (wave * 32)      * 32);
    gload_lds16(A  + (size_t)(tm + srow + 16) * Kdim + k0 + scol,      As0 + (wave * 32 + 16) * 32);
    gload_lds16(A  + (size_t)(tm + srow)      * Kdim + k0 + 32 + scol, As1 + (wave * 32)      * 32);
    gload_lds16(A  + (size_t)(tm + srow + 16) * Kdim + k0 + 32 + scol, As1 + (wave * 32 + 16) * 32);
    gload_lds16(Bt + (size_t)(tn + srow)      * Kdim + k0 + scol,      Bs0 + (wave * 32)      * 32);
    gload_lds16(Bt + (size_t)(tn + srow + 16) * Kdim + k0 + scol,      Bs0 + (wave * 32 + 16) * 32);
    gload_lds16(Bt + (size_t)(tn + srow)      * Kdim + k0 + 32 + scol, Bs1 + (wave * 32)      * 32);
    gload_lds16(Bt + (size_t)(tn + srow + 16) * Kdim + k0 + 32 + scol, Bs1 + (wave * 32 + 16) * 32);
    __syncthreads();
    compute(As0, Bs0);
    compute(As1, Bs1);
  }

  const int fq = (lane >> 4) * 4;
  const int which = tn / D_MODEL;              // block-uniform (128 | 768)
  if (which != 2) {
    const float qs = (which == 0) ? QSCALE : 1.0f;
    unsigned short* Dst = (which == 0) ? Qf : Kf;
    __syncthreads();                           // stage bufs dead -> overlay as Cs
    #pragma unroll
    for (int j = 0; j < 4; j++) {
      int lc = wn + j * 16 + fr;
      float bv = bias[tn + lc];
      #pragma unroll
      for (int i = 0; i < 4; i++)
        #pragma unroll
        for (int r = 0; r < 4; r++)
          smem[(wm + i * 16 + fq + r) * 136 + lc] = bfc((acc[i][j][r] + bv) * qs);
    }
    __syncthreads();
    // 32 tiles x 1KB; thread -> tile tid>>3, 8 coalesced 16B stores
    const int T = tid >> 3;
    const int T_l = T >> 3, T_d = T & 7;
    const int h_off = T_d >> 2, d4 = T_d & 3;
    const int b0 = tm >> 12;
    const int l0 = (tm & 4095) + T_l * 32;
    const int h0 = (tn % D_MODEL) >> 6;
    const size_t hb = (size_t)b0 * NH + h0 + h_off;
    unsigned short* tbase = Dst + ((hb * 128 + (l0 >> 5)) * 4 + d4) * 512;
    const int u = tid & 7;
    #pragma unroll
    for (int c = 0; c < 8; c++) {
      int idx8 = u * 8 + c;                    // (l&31) + 32*dd
      int l5 = idx8 & 31, dd = idx8 >> 5;
      int lc = h_off * 64 + d4 * 16 + dd * 8;
      ulonglong2 v16 = *(const ulonglong2*)(smem + (T_l * 32 + l5) * 136 + lc);
      *(ulonglong2*)(tbase + idx8 * 8) = v16;
    }
  } else {
    // V: proven permuted scatter
    #pragma unroll
    for (int j = 0; j < 4; j++) {
      int col = tn + wn + j * 16 + fr;
      float bv = bias[col];
      int hd = col % D_MODEL;
      int h = hd >> 6, d = hd & 63;
      #pragma unroll
      for (int i = 0; i < 4; i++) {
        #pragma unroll
        for (int r = 0; r < 4; r++) {
          int row = tm + wm + i * 16 + fq + r;
          int b = row >> 12, l = row & 4095;
          float v = acc[i][j][r] + bv;
          size_t hb = (size_t)b * NH + h;
          size_t off = ((hb * 64 + (l >> 6)) * 8 + ((l >> 4) & 3) * 2 + (d >> 5)) * 512
                     + (size_t)((d & 31) + 32 * ((l >> 2) & 1)) * 8
                     + ((l & 3) + 4 * ((l >> 3) & 1));
          Vf[off] = bfc(v);
        }
      }
    }
  }
}

// ---------------- GEMM2 (128x64, 2 waves): fp32 epilogue --------------------
// Same 2-K-steps-per-barrier restructure.
__global__ __launch_bounds__(128) void gemm_out(const unsigned short* __restrict__ A,
                                                const unsigned short* __restrict__ Bt,
                                                const float* __restrict__ bias,
                                                float* __restrict__ Out,
                                                int M, int N, int Kdim) {
  __shared__ unsigned short As[2][128 * 32];
  __shared__ unsigned short Bs[2][64 * 32];
  const int tid = threadIdx.x;
  const int lane = tid & 63, wave = tid >> 6;   // 2 waves
  const int tm = blockIdx.x * 128, tn = blockIdx.y * 64;
  const int wm = wave * 64;
  const int fr = lane & 15, fk8 = (lane >> 4) * 8;
  const int srA = wave * 64 + (lane >> 2);
  const int srB = wave * 32 + (lane >> 2);
  const int scol = (lane & 3) * 8;

  f32x4 acc[4][4] = {};

  auto compute = [&](const unsigned short* Asb, const unsigned short* Bsb) {
    bf16x8 af[4], bfr[4];
    #pragma unroll
    for (int i = 0; i < 4; i++) {
      af[i]  = *(const bf16x8*)(Asb + (wm + i * 16 + fr) * 32 + fk8);
      bfr[i] = *(const bf16x8*)(Bsb + (i * 16 + fr) * 32 + fk8);
    }
    #pragma unroll
    for (int i = 0; i < 4; i++)
      #pragma unroll
      for (int j = 0; j < 4; j++)
        acc[i][j] = __builtin_amdgcn_mfma_f32_16x16x32_bf16(af[i], bfr[j], acc[i][j], 0, 0, 0);
  };

  for (int k0 = 0; k0 < Kdim; k0 += 64) {
    __syncthreads();
    #pragma unroll
    for (int half = 0; half < 2; half++) {
      int kk = k0 + half * 32;
      gload_lds16(A  + (size_t)(tm + srA)      * Kdim + kk + scol, &As[half][(wave * 64)      * 32]);
      gload_lds16(A  + (size_t)(tm + srA + 16) * Kdim + kk + scol, &As[half][(wave * 64 + 16) * 32]);
      gload_lds16(A  + (size_t)(tm + srA + 32) * Kdim + kk + scol, &As[half][(wave * 64 + 32) * 32]);
      gload_lds16(A  + (size_t)(tm + srA + 48) * Kdim + kk + scol, &As[half][(wave * 64 + 48) * 32]);
      gload_lds16(Bt + (size_t)(tn + srB)      * Kdim + kk + scol, &Bs[half][(wave * 32)      * 32]);
      gload_lds16(Bt + (size_t)(tn + srB + 16) * Kdim + kk + scol, &Bs[half][(wave * 32 + 16) * 32]);
    }
    __syncthreads();
    compute(As[0], Bs[0]);
    compute(As[1], Bs[1]);
  }

  const int fq = (lane >> 4) * 4;
  #pragma unroll
  for (int i = 0; i < 4; i++)
    #pragma unroll
    for (int j = 0; j < 4; j++) {
      int col = tn + j * 16 + fr;
      float bv = bias[col];
      #pragma unroll
      for (int r = 0; r < 4; r++) {
        int row = tm + wm + i * 16 + fq + r;
        Out[(size_t)row * N + col] = acc[i][j][r] + bv;
      }
    }
}

// ---------------- flash attention: EXACT r14 proven body (83.6 us) ---------
// Grid 3072 x 128thr (2 waves). Block = one (tile t, half s) of one bh;
// wave w takes 32-kv chunks c === w (mod 2) of [0, 2t+s]. P = exp2(S) (no
// max; cancels in normalization), l via ones-MFMA col 0, permuted-V PV,
// elementwise LDS merge. VGPR 64 + 48 AGPR: sits on the 4-wave/SIMD tier —
// DO NOT add registers (r15/r17/r18 all lost occupancy trying).
#define PVSTEP(P, B, VB0, VB1) do {                                        \
    u32x4 w4;                                                              \
    w4[0] = pk2(P[(B)+0], P[(B)+1]);                                       \
    w4[1] = pk2(P[(B)+2], P[(B)+3]);                                       \
    w4[2] = pk2(P[(B)+4], P[(B)+5]);                                       \
    w4[3] = pk2(P[(B)+6], P[(B)+7]);                                       \
    bf16x8 pa = __builtin_bit_cast(bf16x8, w4);                            \
    oacc0 = __builtin_amdgcn_mfma_f32_32x32x16_bf16(pa, VB0, oacc0, 0,0,0);\
    oacc1 = __builtin_amdgcn_mfma_f32_32x32x16_bf16(pa, VB1, oacc1, 0,0,0);\
    lacc  = __builtin_amdgcn_mfma_f32_32x32x16_bf16(pa, onesB, lacc, 0,0,0);\
  } while(0)

__global__ __launch_bounds__(128) void attn_fwd(const unsigned short* __restrict__ Qf,
                                                const unsigned short* __restrict__ Kf,
                                                const unsigned short* __restrict__ Vf,
                                                unsigned short* __restrict__ O) {
  const int bid = blockIdx.x;
  const int t = 63 - (bid / 48);     // LPT: longest tiles first
  const int r48 = bid % 48;
  const int bh = r48 % 24;
  const int s = r48 / 24;            // 32-row half within the 64-row tile
  const int tid = threadIdx.x;
  const int w = tid >> 6;            // wave 0/1: kv chunks c === w (mod 2)
  const int lane = tid & 63;
  const int l31 = lane & 31, hi = lane >> 5;
  const int Cm1 = 2 * t + s;         // diagonal 32-chunk index (last chunk)

  __shared__ float LoA[16][64];      // wave1 partial oacc0
  __shared__ float LoB[16][64];      // wave1 partial oacc1
  __shared__ float Lsum[2][32];      // per-wave l sums (q-indexed)

  // fragment-tile bases (bytes), all + lane*16
  const char* Kbh = (const char*)Kf + ((size_t)bh * 512) * 1024 + lane * 16;
  const char* Vbh = (const char*)Vf + ((size_t)bh * 512) * 1024 + lane * 16;
  const int b = bh / NH, h = bh % NH;

  bf16x8 qf[4];
  const char* Qb_ = (const char*)Qf + (((size_t)bh * 128 + t * 2 + s) * 4) * 1024 + lane * 16;
  #pragma unroll
  for (int f = 0; f < 4; f++) qf[f] = *(const bf16x8*)(Qb_ + f * 1024);

  // ones B-fragment: column 0 only (n = l31 == 0), all 16 k-rows
  unsigned int ow = (l31 == 0) ? 0x3F803F80u : 0u;
  u32x4 o4; o4[0] = ow; o4[1] = ow; o4[2] = ow; o4[3] = ow;
  const bf16x8 onesB = __builtin_bit_cast(bf16x8, o4);

  f32x16 zf = {};                    // persistent zero C-operand
  f32x16 oacc0 = {}, oacc1 = {}, lacc = {};

  // this wave's 32-kv chunks: c = w, w+2, ..., <= Cm1
  for (int c = w; c <= Cm1; c += 2) {
    const char* kp = Kbh + (size_t)c * 4096;
    bf16x8 kf0 = *(const bf16x8*)(kp);
    bf16x8 kf1 = *(const bf16x8*)(kp + 1024);
    bf16x8 kf2 = *(const bf16x8*)(kp + 2048);
    bf16x8 kf3 = *(const bf16x8*)(kp + 3072);
    const char* vp = Vbh + (size_t)c * 4096;
    bf16x8 v0a = *(const bf16x8*)(vp);          // early V (kv 0-15), in flight
    bf16x8 v0b = *(const bf16x8*)(vp + 1024);   // during QK + softmax

    __builtin_amdgcn_s_setprio(1);
    f32x16 sS = __builtin_amdgcn_mfma_f32_32x32x16_bf16(kf0, qf[0], zf, 0, 0, 0);
    sS = __builtin_amdgcn_mfma_f32_32x32x16_bf16(kf1, qf[1], sS, 0, 0, 0);
    sS = __builtin_amdgcn_mfma_f32_32x32x16_bf16(kf2, qf[2], sS, 0, 0, 0);
    sS = __builtin_amdgcn_mfma_f32_32x32x16_bf16(kf3, qf[3], sS, 0, 0, 0);
    __builtin_amdgcn_s_setprio(0);

    if (c == Cm1) {   // diagonal 32-block (only wave s reaches this)
      #pragma unroll
      for (int r = 0; r < 16; r++) {
        int kvo = (r & 3) + 8 * (r >> 2) + 4 * hi;
        if (kvo > l31) sS[r] = -1e30f;
      }
    }

    // P = exp2(S): no max, no offset (cancels in normalization)
    #pragma unroll
    for (int r = 0; r < 16; r++) sS[r] = fexp2(sS[r]);

    __builtin_amdgcn_s_setprio(1);
    PVSTEP(sS, 0, v0a, v0b);
    {
      bf16x8 v1a = *(const bf16x8*)(vp + 2048); // late V (kv 16-31)
      bf16x8 v1b = *(const bf16x8*)(vp + 3072);
      PVSTEP(sS, 8, v1a, v1b);
    }
    __builtin_amdgcn_s_setprio(0);
  }

  // l extraction: lanes l31==0 hold lacc col 0; q = (r&3)+8*(r>>2)+4*hi
  if (l31 == 0) {
    #pragma unroll
    for (int r = 0; r < 16; r++)
      Lsum[w][(r & 3) + 8 * (r >> 2) + 4 * hi] = lacc[r];
  }
  if (w == 1) {
    #pragma unroll
    for (int r = 0; r < 16; r++) {
      LoA[r][lane] = oacc0[r];
      LoB[r][lane] = oacc1[r];
    }
  }
  __syncthreads();

  if (w == 0) {
    float lm = Lsum[0][l31] + Lsum[1][l31];    // this lane's q (=l31)
    const int q0w = t * 64 + s * 32;
    #pragma unroll
    for (int r = 0; r < 16; r++) {
      int qo = (r & 3) + 8 * (r >> 2) + 4 * hi;
      float linv = 1.0f / __shfl(lm, qo);
      float o0 = (oacc0[r] + LoA[r][lane]) * linv;
      float o1 = (oacc1[r] + LoB[r][lane]) * linv;
      size_t base = ((size_t)b * SL + q0w + qo) * D_MODEL + h * DHd;
      O[base + l31]      = bfc(o0);
      O[base + 32 + l31] = bfc(o1);
    }
  }
}

// ---------------- launch ----------------
extern "C" void kernel_launch(void* const* d_in, const int* in_sizes, int n_in,
                              void* d_out, int out_size, void* d_ws, size_t ws_size,
                              hipStream_t stream) {
  (void)in_sizes; (void)n_in; (void)out_size; (void)ws_size;
  const float* x     = (const float*)d_in[0];
  const float* w_qkv = (const float*)d_in[1];
  const float* b_qkv = (const float*)d_in[2];
  const float* w_out = (const float*)d_in[3];
  const float* b_out = (const float*)d_in[4];
  float* out = (float*)d_out;

  unsigned short* p = (unsigned short*)d_ws;
  unsigned short* xb    = p; p += (size_t)BLr * D_MODEL;
  unsigned short* wqkvT = p; p += (size_t)N3 * D_MODEL;
  unsigned short* woutT = p; p += (size_t)D_MODEL * D_MODEL;
  unsigned short* Qf    = p; p += (size_t)NB * NH * SL * DHd;  // fragment-tiled, *log2e/8
  unsigned short* Kf    = p; p += (size_t)NB * NH * SL * DHd;  // fragment-tiled
  unsigned short* Vf    = p; p += (size_t)NB * NH * SL * DHd;  // fragment-tiled (permuted V^T)
  unsigned short* Ob    = p;                                   // [b*l][768] bf16

  cast_f32_bf16<<<(BLr * D_MODEL / 4 + 255) / 256, 256, 0, stream>>>(x, xb, BLr * D_MODEL / 4);
  transpose_cast2<<<dim3(96, 24), 256, 0, stream>>>(w_qkv, wqkvT, w_out, woutT);
  gemm_qkv<<<dim3(BLr / 128, N3 / 128), 256, 0, stream>>>(xb, wqkvT, b_qkv, Qf, Kf, Vf,
                                                          BLr, N3, D_MODEL);
  attn_fwd<<<3072, 128, 0, stream>>>(Qf, Kf, Vf, Ob);
  gemm_out<<<dim3(BLr / 128, D_MODEL / 64), 128, 0, stream>>>(Ob, woutT, b_out, out,
                                                              BLr, D_MODEL, D_MODEL);
}

// Round 21
// 171.000 us; speedup vs baseline: 1.0325x; 1.0325x over previous
//
#include <hip/hip_runtime.h>
#include <hip/hip_bf16.h>

#define D_MODEL 768
#define NH 12
#define DHd 64
#define NB 2
#define SL 4096
#define BLr (NB*SL)      // 8192 rows
#define N3 (3*D_MODEL)   // 2304
#define QSCALE 0.18033688011112042f   // 0.125 * log2(e): softmax in log2 domain

typedef __bf16 bf16x8 __attribute__((ext_vector_type(8)));
typedef float f32x4 __attribute__((ext_vector_type(4)));
typedef float f32x16 __attribute__((ext_vector_type(16)));
typedef unsigned int u32x4 __attribute__((ext_vector_type(4)));

__device__ __forceinline__ unsigned short f2bf(float f) {
  unsigned int u = __float_as_uint(f);
  u = (u + 0x7FFFu + ((u >> 16) & 1u)) >> 16;
  return (unsigned short)u;
}
__device__ __forceinline__ unsigned short bfc(float f) {
  __bf16 h = (__bf16)f;
  return __builtin_bit_cast(unsigned short, h);
}
__device__ __forceinline__ float fexp2(float x) {
  float r; asm("v_exp_f32 %0, %1" : "=v"(r) : "v"(x)); return r;
}
// packed bf16 conversion: dst.lo = bf16(lo), dst.hi = bf16(hi) — single VALU op
__device__ __forceinline__ unsigned int pk2(float lo, float hi2) {
  unsigned int r;
  asm("v_cvt_pk_bf16_f32 %0, %1, %2" : "=v"(r) : "v"(lo), "v"(hi2));
  return r;
}
// async global->LDS, 16B per lane; LDS dest = wave-uniform base + lane*16
__device__ __forceinline__ void gload_lds16(const void* g, void* l) {
  __builtin_amdgcn_global_load_lds(
      (const __attribute__((address_space(1))) void*)g,
      (__attribute__((address_space(3))) void*)l, 16, 0, 0);
}

// ---------------- prep kernels ----------------
__global__ __launch_bounds__(256) void cast_f32_bf16(const float* __restrict__ in,
                                                     unsigned short* __restrict__ out, int n4) {
  int i = blockIdx.x * 256 + threadIdx.x;
  if (i >= n4) return;
  float4 v = reinterpret_cast<const float4*>(in)[i];
  ushort4 o;
  o.x = f2bf(v.x); o.y = f2bf(v.y); o.z = f2bf(v.z); o.w = f2bf(v.w);
  reinterpret_cast<ushort4*>(out)[i] = o;
}

// fused: transpose+cast w_qkv (768x2304 -> [2304][768]) and w_out (768x768)
__global__ __launch_bounds__(256) void transpose_cast2(const float* __restrict__ wq,
                                                       unsigned short* __restrict__ oq,
                                                       const float* __restrict__ wo,
                                                       unsigned short* __restrict__ oo) {
  __shared__ float t[32][33];
  const int bx = blockIdx.x;
  const float* in; unsigned short* out; int R, C, c0;
  if (bx < 72) { in = wq; out = oq; R = 768; C = 2304; c0 = bx * 32; }
  else         { in = wo; out = oo; R = 768; C = 768;  c0 = (bx - 72) * 32; }
  int r0 = blockIdx.y * 32;
  int tx = threadIdx.x & 31, ty = threadIdx.x >> 5;
  #pragma unroll
  for (int i = 0; i < 32; i += 8) t[ty + i][tx] = in[(size_t)(r0 + ty + i) * C + c0 + tx];
  __syncthreads();
  #pragma unroll
  for (int i = 0; i < 32; i += 8) out[(size_t)(c0 + ty + i) * R + r0 + tx] = f2bf(t[tx][ty + i]);
}

// ---------------- GEMM1 (128x128, 4 waves): QKV fragment-tiled epilogue -----
// Q/K blocks: LDS-staged epilogue -> coalesced 16B fragment-tile stores.
// V blocks: proven direct scatter (permuted layout).
__global__ __launch_bounds__(256) void gemm_qkv(const unsigned short* __restrict__ A,
                                                const unsigned short* __restrict__ Bt,
                                                const float* __restrict__ bias,
                                                unsigned short* __restrict__ Qf,
                                                unsigned short* __restrict__ Kf,
                                                unsigned short* __restrict__ Vf,
                                                int M, int N, int Kdim) {
  __shared__ unsigned short smem[128 * 136];   // As|Bs during loop; Cs after
  unsigned short* As = smem;                   // 128*32
  unsigned short* Bs = smem + 128 * 32;
  const int tid = threadIdx.x;
  const int lane = tid & 63, wave = tid >> 6;
  const int tm = blockIdx.x * 128, tn = blockIdx.y * 128;
  const int wm = (wave >> 1) * 64, wn = (wave & 1) * 64;
  const int fr = lane & 15, fk8 = (lane >> 4) * 8;
  const int srow = wave * 32 + (lane >> 2);
  const int scol = (lane & 3) * 8;

  f32x4 acc[4][4] = {};

  for (int k0 = 0; k0 < Kdim; k0 += 32) {
    __syncthreads();
    gload_lds16(A  + (size_t)(tm + srow)      * Kdim + k0 + scol, As + (wave * 32)      * 32);
    gload_lds16(A  + (size_t)(tm + srow + 16) * Kdim + k0 + scol, As + (wave * 32 + 16) * 32);
    gload_lds16(Bt + (size_t)(tn + srow)      * Kdim + k0 + scol, Bs + (wave * 32)      * 32);
    gload_lds16(Bt + (size_t)(tn + srow + 16) * Kdim + k0 + scol, Bs + (wave * 32 + 16) * 32);
    __syncthreads();

    bf16x8 af[4], bfr[4];
    #pragma unroll
    for (int i = 0; i < 4; i++) {
      af[i]  = *(const bf16x8*)(As + (wm + i * 16 + fr) * 32 + fk8);
      bfr[i] = *(const bf16x8*)(Bs + (wn + i * 16 + fr) * 32 + fk8);
    }
    #pragma unroll
    for (int i = 0; i < 4; i++)
      #pragma unroll
      for (int j = 0; j < 4; j++)
        acc[i][j] = __builtin_amdgcn_mfma_f32_16x16x32_bf16(af[i], bfr[j], acc[i][j], 0, 0, 0);
  }

  const int fq = (lane >> 4) * 4;
  const int which = tn / D_MODEL;              // block-uniform (128 | 768)
  if (which != 2) {
    const float qs = (which == 0) ? QSCALE : 1.0f;
    unsigned short* Dst = (which == 0) ? Qf : Kf;
    __syncthreads();                           // As/Bs dead -> overlay as Cs
    #pragma unroll
    for (int j = 0; j < 4; j++) {
      int lc = wn + j * 16 + fr;
      float bv = bias[tn + lc];
      #pragma unroll
      for (int i = 0; i < 4; i++)
        #pragma unroll
        for (int r = 0; r < 4; r++)
          smem[(wm + i * 16 + fq + r) * 136 + lc] = bfc((acc[i][j][r] + bv) * qs);
    }
    __syncthreads();
    // 32 tiles x 1KB; thread -> tile tid>>3, 8 coalesced 16B stores
    const int T = tid >> 3;
    const int T_l = T >> 3, T_d = T & 7;
    const int h_off = T_d >> 2, d4 = T_d & 3;
    const int b0 = tm >> 12;
    const int l0 = (tm & 4095) + T_l * 32;
    const int h0 = (tn % D_MODEL) >> 6;
    const size_t hb = (size_t)b0 * NH + h0 + h_off;
    unsigned short* tbase = Dst + ((hb * 128 + (l0 >> 5)) * 4 + d4) * 512;
    const int u = tid & 7;
    #pragma unroll
    for (int c = 0; c < 8; c++) {
      int idx8 = u * 8 + c;                    // (l&31) + 32*dd
      int l5 = idx8 & 31, dd = idx8 >> 5;
      int lc = h_off * 64 + d4 * 16 + dd * 8;
      ulonglong2 v16 = *(const ulonglong2*)(smem + (T_l * 32 + l5) * 136 + lc);
      *(ulonglong2*)(tbase + idx8 * 8) = v16;
    }
  } else {
    // V: proven permuted scatter
    #pragma unroll
    for (int j = 0; j < 4; j++) {
      int col = tn + wn + j * 16 + fr;
      float bv = bias[col];
      int hd = col % D_MODEL;
      int h = hd >> 6, d = hd & 63;
      #pragma unroll
      for (int i = 0; i < 4; i++) {
        #pragma unroll
        for (int r = 0; r < 4; r++) {
          int row = tm + wm + i * 16 + fq + r;
          int b = row >> 12, l = row & 4095;
          float v = acc[i][j][r] + bv;
          size_t hb = (size_t)b * NH + h;
          size_t off = ((hb * 64 + (l >> 6)) * 8 + ((l >> 4) & 3) * 2 + (d >> 5)) * 512
                     + (size_t)((d & 31) + 32 * ((l >> 2) & 1)) * 8
                     + ((l & 3) + 4 * ((l >> 3) & 1));
          Vf[off] = bfc(v);
        }
      }
    }
  }
}

// ---------------- GEMM2 (128x64, 2 waves): fp32 epilogue --------------------
__global__ __launch_bounds__(128) void gemm_out(const unsigned short* __restrict__ A,
                                                const unsigned short* __restrict__ Bt,
                                                const float* __restrict__ bias,
                                                float* __restrict__ Out,
                                                int M, int N, int Kdim) {
  __shared__ unsigned short As[128 * 32];
  __shared__ unsigned short Bs[64 * 32];
  const int tid = threadIdx.x;
  const int lane = tid & 63, wave = tid >> 6;   // 2 waves
  const int tm = blockIdx.x * 128, tn = blockIdx.y * 64;
  const int wm = wave * 64;
  const int fr = lane & 15, fk8 = (lane >> 4) * 8;
  const int srA = wave * 64 + (lane >> 2);
  const int srB = wave * 32 + (lane >> 2);
  const int scol = (lane & 3) * 8;

  f32x4 acc[4][4] = {};

  for (int k0 = 0; k0 < Kdim; k0 += 32) {
    __syncthreads();
    gload_lds16(A  + (size_t)(tm + srA)      * Kdim + k0 + scol, As + (wave * 64)      * 32);
    gload_lds16(A  + (size_t)(tm + srA + 16) * Kdim + k0 + scol, As + (wave * 64 + 16) * 32);
    gload_lds16(A  + (size_t)(tm + srA + 32) * Kdim + k0 + scol, As + (wave * 64 + 32) * 32);
    gload_lds16(A  + (size_t)(tm + srA + 48) * Kdim + k0 + scol, As + (wave * 64 + 48) * 32);
    gload_lds16(Bt + (size_t)(tn + srB)      * Kdim + k0 + scol, Bs + (wave * 32)      * 32);
    gload_lds16(Bt + (size_t)(tn + srB + 16) * Kdim + k0 + scol, Bs + (wave * 32 + 16) * 32);
    __syncthreads();

    bf16x8 af[4], bfr[4];
    #pragma unroll
    for (int i = 0; i < 4; i++) {
      af[i]  = *(const bf16x8*)(As + (wm + i * 16 + fr) * 32 + fk8);
      bfr[i] = *(const bf16x8*)(Bs + (i * 16 + fr) * 32 + fk8);
    }
    #pragma unroll
    for (int i = 0; i < 4; i++)
      #pragma unroll
      for (int j = 0; j < 4; j++)
        acc[i][j] = __builtin_amdgcn_mfma_f32_16x16x32_bf16(af[i], bfr[j], acc[i][j], 0, 0, 0);
  }

  const int fq = (lane >> 4) * 4;
  #pragma unroll
  for (int i = 0; i < 4; i++)
    #pragma unroll
    for (int j = 0; j < 4; j++) {
      int col = tn + j * 16 + fr;
      float bv = bias[col];
      #pragma unroll
      for (int r = 0; r < 4; r++) {
        int row = tm + wm + i * 16 + fq + r;
        Out[(size_t)row * N + col] = acc[i][j][r] + bv;
      }
    }
}

// ---------------- flash attention: EXACT r14 proven body (83.6 us) ---------
// Grid 3072 x 128thr (2 waves). Block = one (tile t, half s) of one bh;
// wave w takes 32-kv chunks c === w (mod 2) of [0, 2t+s]. P = exp2(S) (no
// max; cancels in normalization), l via ones-MFMA col 0, permuted-V PV,
// elementwise LDS merge. VGPR 64 + 48 AGPR: sits on the 4-wave/SIMD tier —
// DO NOT add registers (r15/r17/r18 all lost occupancy trying).
#define PVSTEP(P, B, VB0, VB1) do {                                        \
    u32x4 w4;                                                              \
    w4[0] = pk2(P[(B)+0], P[(B)+1]);                                       \
    w4[1] = pk2(P[(B)+2], P[(B)+3]);                                       \
    w4[2] = pk2(P[(B)+4], P[(B)+5]);                                       \
    w4[3] = pk2(P[(B)+6], P[(B)+7]);                                       \
    bf16x8 pa = __builtin_bit_cast(bf16x8, w4);                            \
    oacc0 = __builtin_amdgcn_mfma_f32_32x32x16_bf16(pa, VB0, oacc0, 0,0,0);\
    oacc1 = __builtin_amdgcn_mfma_f32_32x32x16_bf16(pa, VB1, oacc1, 0,0,0);\
    lacc  = __builtin_amdgcn_mfma_f32_32x32x16_bf16(pa, onesB, lacc, 0,0,0);\
  } while(0)

__global__ __launch_bounds__(128) void attn_fwd(const unsigned short* __restrict__ Qf,
                                                const unsigned short* __restrict__ Kf,
                                                const unsigned short* __restrict__ Vf,
                                                unsigned short* __restrict__ O) {
  const int bid = blockIdx.x;
  const int t = 63 - (bid / 48);     // LPT: longest tiles first
  const int r48 = bid % 48;
  const int bh = r48 % 24;
  const int s = r48 / 24;            // 32-row half within the 64-row tile
  const int tid = threadIdx.x;
  const int w = tid >> 6;            // wave 0/1: kv chunks c === w (mod 2)
  const int lane = tid & 63;
  const int l31 = lane & 31, hi = lane >> 5;
  const int Cm1 = 2 * t + s;         // diagonal 32-chunk index (last chunk)

  __shared__ float LoA[16][64];      // wave1 partial oacc0
  __shared__ float LoB[16][64];      // wave1 partial oacc1
  __shared__ float Lsum[2][32];      // per-wave l sums (q-indexed)

  // fragment-tile bases (bytes), all + lane*16
  const char* Kbh = (const char*)Kf + ((size_t)bh * 512) * 1024 + lane * 16;
  const char* Vbh = (const char*)Vf + ((size_t)bh * 512) * 1024 + lane * 16;
  const int b = bh / NH, h = bh % NH;

  bf16x8 qf[4];
  const char* Qb_ = (const char*)Qf + (((size_t)bh * 128 + t * 2 + s) * 4) * 1024 + lane * 16;
  #pragma unroll
  for (int f = 0; f < 4; f++) qf[f] = *(const bf16x8*)(Qb_ + f * 1024);

  // ones B-fragment: column 0 only (n = l31 == 0), all 16 k-rows
  unsigned int ow = (l31 == 0) ? 0x3F803F80u : 0u;
  u32x4 o4; o4[0] = ow; o4[1] = ow; o4[2] = ow; o4[3] = ow;
  const bf16x8 onesB = __builtin_bit_cast(bf16x8, o4);

  f32x16 zf = {};                    // persistent zero C-operand
  f32x16 oacc0 = {}, oacc1 = {}, lacc = {};

  // this wave's 32-kv chunks: c = w, w+2, ..., <= Cm1
  for (int c = w; c <= Cm1; c += 2) {
    const char* kp = Kbh + (size_t)c * 4096;
    bf16x8 kf0 = *(const bf16x8*)(kp);
    bf16x8 kf1 = *(const bf16x8*)(kp + 1024);
    bf16x8 kf2 = *(const bf16x8*)(kp + 2048);
    bf16x8 kf3 = *(const bf16x8*)(kp + 3072);
    const char* vp = Vbh + (size_t)c * 4096;
    bf16x8 v0a = *(const bf16x8*)(vp);          // early V (kv 0-15), in flight
    bf16x8 v0b = *(const bf16x8*)(vp + 1024);   // during QK + softmax

    __builtin_amdgcn_s_setprio(1);
    f32x16 sS = __builtin_amdgcn_mfma_f32_32x32x16_bf16(kf0, qf[0], zf, 0, 0, 0);
    sS = __builtin_amdgcn_mfma_f32_32x32x16_bf16(kf1, qf[1], sS, 0, 0, 0);
    sS = __builtin_amdgcn_mfma_f32_32x32x16_bf16(kf2, qf[2], sS, 0, 0, 0);
    sS = __builtin_amdgcn_mfma_f32_32x32x16_bf16(kf3, qf[3], sS, 0, 0, 0);
    __builtin_amdgcn_s_setprio(0);

    if (c == Cm1) {   // diagonal 32-block (only wave s reaches this)
      #pragma unroll
      for (int r = 0; r < 16; r++) {
        int kvo = (r & 3) + 8 * (r >> 2) + 4 * hi;
        if (kvo > l31) sS[r] = -1e30f;
      }
    }

    // P = exp2(S): no max, no offset (cancels in normalization)
    #pragma unroll
    for (int r = 0; r < 16; r++) sS[r] = fexp2(sS[r]);

    __builtin_amdgcn_s_setprio(1);
    PVSTEP(sS, 0, v0a, v0b);
    {
      bf16x8 v1a = *(const bf16x8*)(vp + 2048); // late V (kv 16-31)
      bf16x8 v1b = *(const bf16x8*)(vp + 3072);
      PVSTEP(sS, 8, v1a, v1b);
    }
    __builtin_amdgcn_s_setprio(0);
  }

  // l extraction: lanes l31==0 hold lacc col 0; q = (r&3)+8*(r>>2)+4*hi
  if (l31 == 0) {
    #pragma unroll
    for (int r = 0; r < 16; r++)
      Lsum[w][(r & 3) + 8 * (r >> 2) + 4 * hi] = lacc[r];
  }
  if (w == 1) {
    #pragma unroll
    for (int r = 0; r < 16; r++) {
      LoA[r][lane] = oacc0[r];
      LoB[r][lane] = oacc1[r];
    }
  }
  __syncthreads();

  if (w == 0) {
    float lm = Lsum[0][l31] + Lsum[1][l31];    // this lane's q (=l31)
    const int q0w = t * 64 + s * 32;
    #pragma unroll
    for (int r = 0; r < 16; r++) {
      int qo = (r & 3) + 8 * (r >> 2) + 4 * hi;
      float linv = 1.0f / __shfl(lm, qo);
      float o0 = (oacc0[r] + LoA[r][lane]) * linv;
      float o1 = (oacc1[r] + LoB[r][lane]) * linv;
      size_t base = ((size_t)b * SL + q0w + qo) * D_MODEL + h * DHd;
      O[base + l31]      = bfc(o0);
      O[base + 32 + l31] = bfc(o1);
    }
  }
}

// ---------------- launch ----------------
extern "C" void kernel_launch(void* const* d_in, const int* in_sizes, int n_in,
                              void* d_out, int out_size, void* d_ws, size_t ws_size,
                              hipStream_t stream) {
  (void)in_sizes; (void)n_in; (void)out_size; (void)ws_size;
  const float* x     = (const float*)d_in[0];
  const float* w_qkv = (const float*)d_in[1];
  const float* b_qkv = (const float*)d_in[2];
  const float* w_out = (const float*)d_in[3];
  const float* b_out = (const float*)d_in[4];
  float* out = (float*)d_out;

  unsigned short* p = (unsigned short*)d_ws;
  unsigned short* xb    = p; p += (size_t)BLr * D_MODEL;
  unsigned short* wqkvT = p; p += (size_t)N3 * D_MODEL;
  unsigned short* woutT = p; p += (size_t)D_MODEL * D_MODEL;
  unsigned short* Qf    = p; p += (size_t)NB * NH * SL * DHd;  // fragment-tiled, *log2e/8
  unsigned short* Kf    = p; p += (size_t)NB * NH * SL * DHd;  // fragment-tiled
  unsigned short* Vf    = p; p += (size_t)NB * NH * SL * DHd;  // fragment-tiled (permuted V^T)
  unsigned short* Ob    = p;                                   // [b*l][768] bf16

  cast_f32_bf16<<<(BLr * D_MODEL / 4 + 255) / 256, 256, 0, stream>>>(x, xb, BLr * D_MODEL / 4);
  transpose_cast2<<<dim3(96, 24), 256, 0, stream>>>(w_qkv, wqkvT, w_out, woutT);
  gemm_qkv<<<dim3(BLr / 128, N3 / 128), 256, 0, stream>>>(xb, wqkvT, b_qkv, Qf, Kf, Vf,
                                                          BLr, N3, D_MODEL);
  attn_fwd<<<3072, 128, 0, stream>>>(Qf, Kf, Vf, Ob);
  gemm_out<<<dim3(BLr / 128, D_MODEL / 64), 128, 0, stream>>>(Ob, woutT, b_out, out,
                                                              BLr, D_MODEL, D_MODEL);
}